// Round 3
// baseline (349.486 us; speedup 1.0000x reference)
//
#include <hip/hip_runtime.h>

#define BB 8
#define CH 256
#define HH 96
#define WW 192
#define HW (HH*WW)            // 18432
#define ND 25
#define TH 16                 // tile rows per block
#define TW 64                 // tile cols per block
#define S2H 24                // TH + 8 halo
#define S2W 72                // TW + 8 halo
#define S2Q (S2H*S2W/4)       // 432 float4 staging slots
#define NTHR 256
#define OUTSZ (BB*ND*HH*WW)   // 3686400

// One pipeline per 256-thread (4-wave) block: 16x64 spatial tile, channel
// group g = blockIdx.y (G groups, sizes differing by <=1). in2 halo tile
// double-buffered in LDS; in1 straight to regs. ~150 unified regs -> 3
// blocks/CU = 12 waves/CU; grid 144*G <= 768 => single dispatch generation.
__global__ __launch_bounds__(NTHR, 3)
void corr_partial(const float* __restrict__ in1, const float* __restrict__ in2,
                  float* __restrict__ part, int G) {
  __shared__ __align__(16) float s2[2][S2H*S2W];  // 13.8 KB

  const int tile = blockIdx.x;
  const int b    = tile / 18;
  const int rem  = tile - b*18;
  const int h0   = (rem / 3) * TH;
  const int w0   = (rem % 3) * TW;
  const int t    = threadIdx.x;
  const int r    = t >> 4;            // 0..15 tile row
  const int c0   = (t & 15) << 2;     // 0..60 tile col (quad)

  const int g      = blockIdx.y;
  const int cb     = CH / G, cr = CH % G;
  const int cBegin = g * cb + (g < cr ? g : cr);
  const int cCount = cb + (g < cr ? 1 : 0);

  const size_t bplane = (size_t)b * CH * HW;
  const float* in1b = in1 + bplane;
  const float* in2b = in2 + bplane;

  // Staging slot 0 (all 256 threads): slot = t -> (row, quad) of 24x72 tile.
  const int s0row = t / 18, s0q = t - (t/18)*18;
  const int g0r = h0 + s0row - 4, g0c = w0 + (s0q << 2) - 4;
  const bool v0 = ((unsigned)g0r < HH) & ((unsigned)g0c <= (unsigned)(WW-4));
  const float* src0 = in2b + (size_t)cBegin*HW + (v0 ? (g0r*WW + g0c) : 0);
  const int lofs0 = s0row*S2W + (s0q << 2);

  // Staging slot 1 (t < 176): slot = t + 256.
  const int t1 = t + 256;
  const bool has1 = t1 < S2Q;
  const int s1row = t1 / 18, s1q = t1 - (t1/18)*18;
  const int g1r = h0 + s1row - 4, g1c = w0 + (s1q << 2) - 4;
  const bool v1 = has1 & ((unsigned)g1r < HH) & ((unsigned)g1c <= (unsigned)(WW-4));
  const float* src1 = in2b + (size_t)cBegin*HW + (v1 ? (g1r*WW + g1c) : 0);
  const int lofs1 = has1 ? (s1row*S2W + (s1q << 2)) : lofs0;

  const float* p1 = in1b + (size_t)cBegin*HW + (h0 + r)*WW + (w0 + c0);

  float4 acc[ND];
  #pragma unroll
  for (int d = 0; d < ND; ++d) acc[d] = make_float4(0.f, 0.f, 0.f, 0.f);
  const float4 z4 = make_float4(0.f, 0.f, 0.f, 0.f);

  // Prologue: stage first channel into buffer 0.
  {
    float4 x0 = v0 ? *(const float4*)src0 : z4;
    *(float4*)&s2[0][lofs0] = x0;
    if (has1) {
      float4 x1 = v1 ? *(const float4*)src1 : z4;
      *(float4*)&s2[0][lofs1] = x1;
    }
  }
  float4 a = *(const float4*)p1;
  __syncthreads();

  for (int cc = 0; cc < cCount; ++cc) {
    const int cur = cc & 1;
    float4 sv0 = z4, sv1 = z4, an = z4;
    const bool more = (cc + 1) < cCount;
    // 1) issue next channel's global loads early (hide HBM latency)
    if (more) {
      const size_t adv = (size_t)(cc + 1) * HW;
      if (v0) sv0 = *(const float4*)(src0 + adv);
      if (v1) sv1 = *(const float4*)(src1 + adv);
      an = *(const float4*)(p1 + adv);
    }
    // 2) compute on current LDS buffer
    const float* sbase = &s2[cur][0];
    #pragma unroll
    for (int dyi = 0; dyi < 5; ++dyi) {
      const float* rowp = sbase + (r + 2*dyi)*S2W + c0;
      float wv[12];
      *(float4*)&wv[0] = *(const float4*)(rowp);
      *(float4*)&wv[4] = *(const float4*)(rowp + 4);
      *(float4*)&wv[8] = *(const float4*)(rowp + 8);
      #pragma unroll
      for (int dxi = 0; dxi < 5; ++dxi) {
        float4& A = acc[dyi*5 + dxi];
        A.x = fmaf(a.x, wv[0 + 2*dxi], A.x);
        A.y = fmaf(a.y, wv[1 + 2*dxi], A.y);
        A.z = fmaf(a.z, wv[2 + 2*dxi], A.z);
        A.w = fmaf(a.w, wv[3 + 2*dxi], A.w);
      }
    }
    // 3) late write of staged regs into the other buffer
    if (more) {
      float* dbase = &s2[cur ^ 1][0];
      *(float4*)(dbase + lofs0) = sv0;
      if (has1) *(float4*)(dbase + lofs1) = sv1;
      a = an;
    }
    __syncthreads();
  }

  // Epilogue: scaled partial write, [g][b][d][h][w], coalesced float4.
  const float scale = 1.0f / CH;
  float* pout = part + (size_t)g * OUTSZ
              + ((size_t)b*ND*HH + (h0 + r))*WW + (w0 + c0);
  #pragma unroll
  for (int d = 0; d < ND; ++d) {
    float4 v;
    v.x = acc[d].x * scale; v.y = acc[d].y * scale;
    v.z = acc[d].z * scale; v.w = acc[d].w * scale;
    *(float4*)(pout + (size_t)d*HW) = v;
  }
}

__global__ void corr_reduce(const float* __restrict__ part,
                            float* __restrict__ out, int G) {
  const int n4 = OUTSZ / 4;
  int i = blockIdx.x * 256 + threadIdx.x;
  if (i >= n4) return;
  const float4* p = (const float4*)part;
  float4 s = p[i];
  for (int g = 1; g < G; ++g) {
    float4 v = p[(size_t)g * n4 + i];
    s.x += v.x; s.y += v.y; s.z += v.z; s.w += v.w;
  }
  ((float4*)out)[i] = s;
}

extern "C" void kernel_launch(void* const* d_in, const int* in_sizes, int n_in,
                              void* d_out, int out_size, void* d_ws, size_t ws_size,
                              hipStream_t stream) {
  const float* in1 = (const float*)d_in[0];
  const float* in2 = (const float*)d_in[1];
  float* out = (float*)d_out;

  // G channel groups -> 144*G blocks; G=5 gives 720 <= 768 (3 blocks/CU),
  // one dispatch generation. Degrade if workspace is small.
  int G = 5;
  while (G > 1 && ws_size < (size_t)G * OUTSZ * sizeof(float)) --G;
  float* part = (G == 1) ? out : (float*)d_ws;

  dim3 grid(BB * 18, G);
  corr_partial<<<grid, NTHR, 0, stream>>>(in1, in2, part, G);
  if (G > 1) {
    corr_reduce<<<(OUTSZ/4 + 255)/256, 256, 0, stream>>>((const float*)d_ws, out, G);
  }
}

// Round 4
// 250.590 us; speedup vs baseline: 1.3947x; 1.3947x over previous
//
#include <hip/hip_runtime.h>

#define BB 8
#define CH 256
#define HH 96
#define WW 192
#define HW (HH*WW)            // 18432
#define ND 25
#define TH 4                  // tile rows per block
#define TW 64                 // tile cols per block
#define S2H 12                // TH + 8 halo
#define S2W 72                // TW + 8 halo
#define S2Q (S2H*S2W/4)       // 216 float4 staging slots
#define NTHR 320              // 5 waves: one dy-group each
#define OUTSZ (BB*ND*HH*WW)

// One block = 4x64 spatial tile x ALL 256 channels x ALL 25 disps (G=1, no
// partials). 5 waves; wave g handles dy-group g (5 dx disps) -> acc is only
// 5 x float4 = 20 VGPRs/thread. One shared in2 halo tile (12x72, double-
// buffered LDS) staged once per channel serves all 5 groups. in1 read
// straight to regs (groups share addresses -> L1 hits).
__global__ __launch_bounds__(NTHR, 4)
void corr_kernel(const float* __restrict__ in1, const float* __restrict__ in2,
                 float* __restrict__ out) {
  __shared__ __align__(16) float s2[2][S2H*S2W];  // 6.9 KB

  const int tile = blockIdx.x;
  const int b    = tile / 72;          // 72 tiles per image (24 rows x 3 cols)
  const int rem  = tile - b*72;
  const int h0   = (rem / 3) * TH;
  const int w0   = (rem % 3) * TW;
  const int t    = threadIdx.x;
  const int g    = t >> 6;             // dy group 0..4 (one wave each)
  const int lane = t & 63;
  const int r    = lane >> 4;          // 0..3 tile row
  const int c0   = (lane & 15) << 2;   // 0..60 tile col (quad)

  const size_t bplane = (size_t)b * CH * HW;
  const float* in1b = in1 + bplane;
  const float* in2b = in2 + bplane;

  // Staging: threads 0..215 each own one float4 slot of the 12x72 tile.
  const bool stager = t < S2Q;
  const int srow = t / 18, sq = t - (t/18)*18;
  const int gr = h0 + srow - 4, gc = w0 + (sq << 2) - 4;
  const bool sval = stager & ((unsigned)gr < HH) & ((unsigned)gc <= (unsigned)(WW-4));
  const float* src = in2b + (sval ? (gr*WW + gc) : 0);
  const int lofs = srow*S2W + (sq << 2);

  // Per-thread read base: dy row is fixed per group.
  const int rofs = (r + 2*g)*S2W + c0;

  const float* p1 = in1b + (h0 + r)*WW + (w0 + c0);

  float4 acc[5];
  #pragma unroll
  for (int j = 0; j < 5; ++j) acc[j] = make_float4(0.f, 0.f, 0.f, 0.f);
  const float4 z4 = make_float4(0.f, 0.f, 0.f, 0.f);

  // Prologue: stage channel 0 into buffer 0; load in1 ch 0.
  if (stager) {
    float4 x = sval ? *(const float4*)src : z4;
    *(float4*)&s2[0][lofs] = x;
  }
  float4 a = *(const float4*)p1;
  __syncthreads();

  for (int cc = 0; cc < CH; ++cc) {
    const int cur = cc & 1;
    float4 sv = z4, an = z4;
    const bool more = (cc + 1) < CH;
    // 1) issue next channel's global loads early (hide HBM latency)
    if (more) {
      const size_t adv = (size_t)(cc + 1) * HW;
      if (sval) sv = *(const float4*)(src + adv);
      an = *(const float4*)(p1 + adv);
    }
    // 2) compute this group's dy row from current LDS buffer
    {
      const float* rowp = &s2[cur][rofs];
      float wv[12];
      *(float4*)&wv[0] = *(const float4*)(rowp);
      *(float4*)&wv[4] = *(const float4*)(rowp + 4);
      *(float4*)&wv[8] = *(const float4*)(rowp + 8);
      #pragma unroll
      for (int j = 0; j < 5; ++j) {
        float4& A = acc[j];
        A.x = fmaf(a.x, wv[0 + 2*j], A.x);
        A.y = fmaf(a.y, wv[1 + 2*j], A.y);
        A.z = fmaf(a.z, wv[2 + 2*j], A.z);
        A.w = fmaf(a.w, wv[3 + 2*j], A.w);
      }
    }
    // 3) late write of staged reg into the other buffer
    if (more) {
      if (stager) *(float4*)&s2[cur ^ 1][lofs] = sv;
      a = an;
    }
    __syncthreads();
  }

  // Epilogue: direct final output write, coalesced float4 per disp.
  const float scale = 1.0f / CH;
  float* pout = out + ((size_t)(b*ND + g*5)*HH + (h0 + r))*WW + (w0 + c0);
  #pragma unroll
  for (int j = 0; j < 5; ++j) {
    float4 v;
    v.x = acc[j].x * scale; v.y = acc[j].y * scale;
    v.z = acc[j].z * scale; v.w = acc[j].w * scale;
    *(float4*)(pout + (size_t)j*HW) = v;
  }
}

extern "C" void kernel_launch(void* const* d_in, const int* in_sizes, int n_in,
                              void* d_out, int out_size, void* d_ws, size_t ws_size,
                              hipStream_t stream) {
  const float* in1 = (const float*)d_in[0];
  const float* in2 = (const float*)d_in[1];
  float* out = (float*)d_out;
  corr_kernel<<<dim3(BB * 72), NTHR, 0, stream>>>(in1, in2, out);
}